// Round 2
// baseline (5147.127 us; speedup 1.0000x reference)
//
#include <hip/hip_runtime.h>

// PlasticLSTM: T=256, B=32, I=128, H=256, 4H=1024, CLIP=2
// d_in: x[T,B,I], Wx[4H,I], bx[4H], Wh[4H,H], bh[4H], w_mod[1,H], b_mod[1],
//       w_fan[H,1], b_fan[H], alpha[H,H]   (all fp32)
// d_out: hs[T,B,H] ++ h[B,H] ++ c[B,H] ++ hebb[B,H,H]  (fp32, concat flat)

#define TT 256
#define BB 32
#define II 128
#define HH 256
#define G4 1024

typedef _Float16 h2_t __attribute__((ext_vector_type(2)));

__device__ __forceinline__ float sigm(float x) {
    return 1.0f / (1.0f + __expf(-x));
}
__device__ __forceinline__ float tanhfast(float x) {
    return 1.0f - 2.0f / (__expf(2.0f * x) + 1.0f);
}
__device__ __forceinline__ unsigned bf16rne(float x) {
    unsigned u = __builtin_bit_cast(unsigned, x);
    return (u + 0x7fffu + ((u >> 16) & 1u)) >> 16;
}
__device__ __forceinline__ float bflo(unsigned p) {
    return __builtin_bit_cast(float, p << 16);
}
__device__ __forceinline__ float bfhi(unsigned p) {
    return __builtin_bit_cast(float, p & 0xffff0000u);
}
__device__ __forceinline__ unsigned pkh(float lo, float hi) {
    h2_t v;
    v.x = (_Float16)lo;
    v.y = (_Float16)hi;
    return __builtin_bit_cast(unsigned, v);
}
__device__ __forceinline__ float clip2(float x) {
    return __builtin_amdgcn_fmed3f(x, -2.0f, 2.0f);
}

#if __has_builtin(__builtin_amdgcn_fdot2)
__device__ __forceinline__ float dot2(unsigned a, unsigned b, float c) {
    return __builtin_amdgcn_fdot2(__builtin_bit_cast(h2_t, a),
                                  __builtin_bit_cast(h2_t, b), c, false);
}
#else
__device__ __forceinline__ float dot2(unsigned a, unsigned b, float c) {
    h2_t av = __builtin_bit_cast(h2_t, a), bv = __builtin_bit_cast(h2_t, b);
    return c + (float)av.x * (float)bv.x + (float)av.y * (float)bv.y;
}
#endif

// ---------------------------------------------------------------------------
// Wd[r8*1024 + g] = uint4 of 8 f16: Wh[g][8*r8 .. 8*r8+7], adjacent rows
// paired into half2 for v_dot2. Coalesced per-thread load in the scan.
// ---------------------------------------------------------------------------
__global__ __launch_bounds__(256) void prep_wd(const float* __restrict__ Wh,
                                               uint4* __restrict__ Wd) {
    int idx = blockIdx.x * 256 + threadIdx.x;   // 32768 = r8*1024 + g
    int r8 = idx >> 10, g = idx & 1023;
    const float4* s = (const float4*)(Wh + (size_t)g * HH + (r8 << 3));
    float4 a = s[0], b2 = s[1];
    uint4 o;
    o.x = pkh(a.x, a.y);
    o.y = pkh(a.z, a.w);
    o.z = pkh(b2.x, b2.y);
    o.w = pkh(b2.z, b2.w);
    Wd[idx] = o;
}

// ---------------------------------------------------------------------------
// alG[p*256 + k] = packed bf16 { alpha[2p][k], alpha[2p+1][k] }
// ---------------------------------------------------------------------------
__global__ __launch_bounds__(256) void prep_al(const float* __restrict__ alpha,
                                               unsigned* __restrict__ alG) {
    int idx = blockIdx.x * 256 + threadIdx.x;   // 32768 = p*256 + k
    int p = idx >> 8, k = idx & 255;
    float a0 = alpha[(size_t)(2 * p) * HH + k];
    float a1 = alpha[(size_t)(2 * p + 1) * HH + k];
    alG[idx] = bf16rne(a0) | (bf16rne(a1) << 16);
}

// ---------------------------------------------------------------------------
// xf[t,b,g] = sum_i x[t,b,i]*Wx[g,i] + bx[g] + bh[g]
// ---------------------------------------------------------------------------
__global__ __launch_bounds__(256) void xf_gemm(const float* __restrict__ x,
                                               const float* __restrict__ Wx,
                                               const float* __restrict__ bx,
                                               const float* __restrict__ bh,
                                               float* __restrict__ xf) {
    __shared__ float As[64][37];
    __shared__ float Bs[64][37];
    const int tid = threadIdx.x;
    const int tx = tid & 15, ty = tid >> 4;
    const int m0 = blockIdx.y << 6;
    const int n0 = blockIdx.x << 6;
    float c[4][4] = {};

    for (int k0 = 0; k0 < II; k0 += 32) {
#pragma unroll
        for (int hh = 0; hh < 2; ++hh) {
            int row = (tid >> 3) + (hh << 5);
            int col = (tid & 7) << 2;
            float4 va = *(const float4*)(x + (size_t)(m0 + row) * II + k0 + col);
            As[row][col] = va.x; As[row][col + 1] = va.y;
            As[row][col + 2] = va.z; As[row][col + 3] = va.w;
            float4 vb = *(const float4*)(Wx + (size_t)(n0 + row) * II + k0 + col);
            Bs[row][col] = vb.x; Bs[row][col + 1] = vb.y;
            Bs[row][col + 2] = vb.z; Bs[row][col + 3] = vb.w;
        }
        __syncthreads();
#pragma unroll
        for (int kk = 0; kk < 32; ++kk) {
            float a[4], bb[4];
#pragma unroll
            for (int u = 0; u < 4; ++u) a[u] = As[(ty << 2) + u][kk];
#pragma unroll
            for (int v = 0; v < 4; ++v) bb[v] = Bs[(tx << 2) + v][kk];
#pragma unroll
            for (int u = 0; u < 4; ++u)
#pragma unroll
                for (int v = 0; v < 4; ++v)
                    c[u][v] = fmaf(a[u], bb[v], c[u][v]);
        }
        __syncthreads();
    }
    const int n = n0 + (tx << 2);
    float4 bxv = *(const float4*)(bx + n);
    float4 bhv = *(const float4*)(bh + n);
    float4 badd = {bxv.x + bhv.x, bxv.y + bhv.y, bxv.z + bhv.z, bxv.w + bhv.w};
#pragma unroll
    for (int u = 0; u < 4; ++u) {
        int m = m0 + (ty << 2) + u;
        float4 o = {c[u][0] + badd.x, c[u][1] + badd.y,
                    c[u][2] + badd.z, c[u][3] + badd.w};
        *(float4*)(xf + (size_t)m * G4 + n) = o;
    }
}

// ---------------------------------------------------------------------------
// Recurrent scan: one block per batch element, 1024 threads, 2 barriers/step.
// Phase 1 (all waves): deferred hebb update for step t-1 FUSED with plast
//   accumulation for step t (single pass over 64 hebb regs), then the gate
//   matvec via v_dot2 on f16 weights.
// Phase 2 (all waves, redundant x4 across row-groups): gate nonlinearities,
//   c/h/j in registers per thread's own k; waves 0-3 publish h (f32+f16) and
//   the eta partials.
// ---------------------------------------------------------------------------
__global__ __launch_bounds__(1024, 1) void scan_kernel(
    const float* __restrict__ xf,      // [T,B,4H], biases folded
    const uint4* __restrict__ Wd,      // f16 interleaved Wh
    const unsigned* __restrict__ alG,  // packed bf16 alpha pairs
    const float* __restrict__ w_mod,
    const float* __restrict__ b_mod,
    const float* __restrict__ w_fan,
    const float* __restrict__ b_fan,
    float* __restrict__ out) {
    const int b   = blockIdx.x;
    const int tid = threadIdx.x;
    const int k   = tid & (HH - 1);
    const int rg  = tid >> 8;        // 0..3
    const int r0  = rg << 6;

    __shared__ alignas(16) float h32_s[2][HH];
    __shared__ alignas(16) unsigned short hf_s[2][HH];
    __shared__ float fioj_s[G4];
    __shared__ float pp_s[4][HH];
    __shared__ float red_s[4];

    float hebb[64];
#pragma unroll
    for (int u = 0; u < 64; ++u) hebb[u] = 0.0f;

    if (tid < HH) {
        h32_s[0][tid] = 0.0f; h32_s[1][tid] = 0.0f;
        hf_s[0][tid] = 0;     hf_s[1][tid] = 0;
    }
    if (tid < 4) red_s[tid] = 0.0f;
    __syncthreads();

    const float bmod = b_mod[0];
    const float wf = w_fan[k], bf = b_fan[k], wm = w_mod[k];
    float creg = 0.0f, jreg = 0.0f, hnreg = 0.0f;

    const uint4* wbase = Wd + tid;
    const unsigned* abase = alG + ((r0 >> 1) << 8) + k;
    const float* xfp = xf + (size_t)b * G4 + tid;

    for (int t = 0; t < TT; ++t) {
        float xfv = xfp[(size_t)t * BB * G4];   // prefetch early

        // ---- Phase 1a: eta_{t-1}, deferred hebb update + plast(t), fused --
        float eta = tanhfast(((red_s[0] + red_s[1]) + (red_s[2] + red_s[3])) + bmod);
        float mj = fmaf(eta, wf, bf) * jreg;    // 0 at t=0 (jreg=0)
        const float4* hOld4 = (const float4*)h32_s[t & 1];        // h_{t-2}
        const float4* hNew4 = (const float4*)h32_s[(t & 1) ^ 1];  // h_{t-1}
        float pp = 0.0f;
#pragma unroll
        for (int u4 = 0; u4 < 16; ++u4) {
            float4 ho = hOld4[(r0 >> 2) + u4];
            float4 hn = hNew4[(r0 >> 2) + u4];
            unsigned p0 = abase[(2 * u4) << 8];
            unsigned p1 = abase[(2 * u4 + 1) << 8];
            float a0 = bflo(p0), a1 = bfhi(p0), a2 = bflo(p1), a3 = bfhi(p1);
            int e = 4 * u4;
            hebb[e]     = clip2(fmaf(mj, ho.x, hebb[e]));
            pp = fmaf(hn.x * a0, hebb[e], pp);
            hebb[e + 1] = clip2(fmaf(mj, ho.y, hebb[e + 1]));
            pp = fmaf(hn.y * a1, hebb[e + 1], pp);
            hebb[e + 2] = clip2(fmaf(mj, ho.z, hebb[e + 2]));
            pp = fmaf(hn.z * a2, hebb[e + 2], pp);
            hebb[e + 3] = clip2(fmaf(mj, ho.w, hebb[e + 3]));
            pp = fmaf(hn.w * a3, hebb[e + 3], pp);
        }
        pp_s[rg][k] = pp;

        // ---- Phase 1b: gate matvec fioj[tid] via f16 dot2 -----------------
        const uint4* hf4 = (const uint4*)hf_s[(t & 1) ^ 1];
        const uint4* wp = wbase;
        float ac0 = 0.f, ac1 = 0.f, ac2 = 0.f, ac3 = 0.f;
#pragma unroll
        for (int r8 = 0; r8 < 32; ++r8) {
            uint4 w = *wp; wp += 1024;
            uint4 hv = hf4[r8];
            ac0 = dot2(w.x, hv.x, ac0);
            ac1 = dot2(w.y, hv.y, ac1);
            ac2 = dot2(w.z, hv.z, ac2);
            ac3 = dot2(w.w, hv.w, ac3);
        }
        fioj_s[tid] = ((ac0 + ac1) + (ac2 + ac3)) + xfv;
        __syncthreads();

        // ---- Phase 2: cell update, redundant across the 4 row-groups ------
        float fg = sigm(fioj_s[k]);
        float ig = sigm(fioj_s[HH + k]);
        float og = sigm(fioj_s[2 * HH + k]);
        float jp = fioj_s[3 * HH + k]
                 + ((pp_s[0][k] + pp_s[1][k]) + (pp_s[2][k] + pp_s[3][k]));
        jreg = tanhfast(jp);
        creg = fmaf(fg, creg, ig * jreg);
        hnreg = og * tanhfast(creg);
        if (rg == 0) {   // waves 0-3, wave-uniform
            h32_s[t & 1][k] = hnreg;
            _Float16 hh = (_Float16)hnreg;
            hf_s[t & 1][k] = __builtin_bit_cast(unsigned short, hh);
            out[((size_t)t * BB + b) * HH + k] = hnreg;
            float e = creg * wm;
#pragma unroll
            for (int m = 32; m >= 1; m >>= 1) e += __shfl_xor(e, m, 64);
            if ((k & 63) == 0) red_s[k >> 6] = e;
        }
        __syncthreads();
    }

    // ---- Final deferred hebb update (step 255's delta) -------------------
    {
        float eta = tanhfast(((red_s[0] + red_s[1]) + (red_s[2] + red_s[3])) + bmod);
        float mj = fmaf(eta, wf, bf) * jreg;
        const float4* hOld4 = (const float4*)h32_s[0];   // h_254 (TT even)
#pragma unroll
        for (int u4 = 0; u4 < 16; ++u4) {
            float4 ho = hOld4[(r0 >> 2) + u4];
            int e = 4 * u4;
            hebb[e]     = clip2(fmaf(mj, ho.x, hebb[e]));
            hebb[e + 1] = clip2(fmaf(mj, ho.y, hebb[e + 1]));
            hebb[e + 2] = clip2(fmaf(mj, ho.z, hebb[e + 2]));
            hebb[e + 3] = clip2(fmaf(mj, ho.w, hebb[e + 3]));
        }
    }

    const size_t HS = (size_t)TT * BB * HH;
    if (rg == 0) {
        out[HS + (size_t)b * HH + k]           = hnreg;  // h_255
        out[HS + BB * HH + (size_t)b * HH + k] = creg;   // c_255
    }
    float* hb = out + HS + 2 * BB * HH + (size_t)b * HH * HH;
#pragma unroll
    for (int u = 0; u < 64; ++u) {
        hb[(size_t)(r0 + u) * HH + k] = hebb[u];
    }
}

// ---------------------------------------------------------------------------
extern "C" void kernel_launch(void* const* d_in, const int* in_sizes, int n_in,
                              void* d_out, int out_size, void* d_ws,
                              size_t ws_size, hipStream_t stream) {
    const float* x     = (const float*)d_in[0];
    const float* Wx    = (const float*)d_in[1];
    const float* bx    = (const float*)d_in[2];
    const float* Wh    = (const float*)d_in[3];
    const float* bh    = (const float*)d_in[4];
    const float* w_mod = (const float*)d_in[5];
    const float* b_mod = (const float*)d_in[6];
    const float* w_fan = (const float*)d_in[7];
    const float* b_fan = (const float*)d_in[8];
    const float* alpha = (const float*)d_in[9];
    float* out = (float*)d_out;

    float*    xf  = (float*)d_ws;                                  // 32 MiB
    uint4*    Wd  = (uint4*)((char*)d_ws + 33554432);              // 512 KiB
    unsigned* alG = (unsigned*)((char*)d_ws + 33554432 + 524288);  // 128 KiB

    hipLaunchKernelGGL(prep_wd, dim3(128), dim3(256), 0, stream, Wh, Wd);
    hipLaunchKernelGGL(prep_al, dim3(128), dim3(256), 0, stream, alpha, alG);
    hipLaunchKernelGGL(xf_gemm, dim3(16, 128), dim3(256), 0, stream,
                       x, Wx, bx, bh, xf);
    hipLaunchKernelGGL(scan_kernel, dim3(BB), dim3(1024), 0, stream,
                       xf, Wd, alG, w_mod, b_mod, w_fan, b_fan, out);
}

// Round 3
// 2878.854 us; speedup vs baseline: 1.7879x; 1.7879x over previous
//
#include <hip/hip_runtime.h>

// PlasticLSTM: T=256, B=32, I=128, H=256, 4H=1024, CLIP=2
// d_in: x[T,B,I], Wx[4H,I], bx[4H], Wh[4H,H], bh[4H], w_mod[1,H], b_mod[1],
//       w_fan[H,1], b_fan[H], alpha[H,H]   (all fp32)
// d_out: hs[T,B,H] ++ h[B,H] ++ c[B,H] ++ hebb[B,H,H]  (fp32, concat flat)

#define TT 256
#define BB 32
#define II 128
#define HH 256
#define G4 1024

typedef _Float16 h2_t __attribute__((ext_vector_type(2)));

__device__ __forceinline__ float sigm(float x) {
    return 1.0f / (1.0f + __expf(-x));
}
__device__ __forceinline__ float tanhfast(float x) {
    return 1.0f - 2.0f / (__expf(2.0f * x) + 1.0f);
}
__device__ __forceinline__ unsigned bf16rne(float x) {
    unsigned u = __builtin_bit_cast(unsigned, x);
    return (u + 0x7fffu + ((u >> 16) & 1u)) >> 16;
}
__device__ __forceinline__ float bflo(unsigned p) {
    return __builtin_bit_cast(float, p << 16);
}
__device__ __forceinline__ float bfhi(unsigned p) {
    return __builtin_bit_cast(float, p & 0xffff0000u);
}
__device__ __forceinline__ unsigned pkh(float lo, float hi) {
    h2_t v;
    v.x = (_Float16)lo;
    v.y = (_Float16)hi;
    return __builtin_bit_cast(unsigned, v);
}
__device__ __forceinline__ float clip2(float x) {
    return __builtin_amdgcn_fmed3f(x, -2.0f, 2.0f);
}

#if __has_builtin(__builtin_amdgcn_fdot2)
__device__ __forceinline__ float dot2(unsigned a, unsigned b, float c) {
    return __builtin_amdgcn_fdot2(__builtin_bit_cast(h2_t, a),
                                  __builtin_bit_cast(h2_t, b), c, false);
}
#else
__device__ __forceinline__ float dot2(unsigned a, unsigned b, float c) {
    h2_t av = __builtin_bit_cast(h2_t, a), bv = __builtin_bit_cast(h2_t, b);
    return c + (float)av.x * (float)bv.x + (float)av.y * (float)bv.y;
}
#endif

// ---------------------------------------------------------------------------
// Wd[r8*1024 + g] = uint4 of 8 f16: Wh[g][8*r8 .. 8*r8+7]
// ---------------------------------------------------------------------------
__global__ __launch_bounds__(256) void prep_wd(const float* __restrict__ Wh,
                                               uint4* __restrict__ Wd) {
    int idx = blockIdx.x * 256 + threadIdx.x;   // 32768 = r8*1024 + g
    int r8 = idx >> 10, g = idx & 1023;
    const float4* s = (const float4*)(Wh + (size_t)g * HH + (r8 << 3));
    float4 a = s[0], b2 = s[1];
    uint4 o;
    o.x = pkh(a.x, a.y);
    o.y = pkh(a.z, a.w);
    o.z = pkh(b2.x, b2.y);
    o.w = pkh(b2.z, b2.w);
    Wd[idx] = o;
}

// ---------------------------------------------------------------------------
// alG[p*256 + k] = packed bf16 { alpha[2p][k], alpha[2p+1][k] }
// ---------------------------------------------------------------------------
__global__ __launch_bounds__(256) void prep_al(const float* __restrict__ alpha,
                                               unsigned* __restrict__ alG) {
    int idx = blockIdx.x * 256 + threadIdx.x;   // 32768 = p*256 + k
    int p = idx >> 8, k = idx & 255;
    float a0 = alpha[(size_t)(2 * p) * HH + k];
    float a1 = alpha[(size_t)(2 * p + 1) * HH + k];
    alG[idx] = bf16rne(a0) | (bf16rne(a1) << 16);
}

// ---------------------------------------------------------------------------
// xf[t,b,g] = sum_i x[t,b,i]*Wx[g,i] + bx[g] + bh[g]
// ---------------------------------------------------------------------------
__global__ __launch_bounds__(256) void xf_gemm(const float* __restrict__ x,
                                               const float* __restrict__ Wx,
                                               const float* __restrict__ bx,
                                               const float* __restrict__ bh,
                                               float* __restrict__ xf) {
    __shared__ float As[64][37];
    __shared__ float Bs[64][37];
    const int tid = threadIdx.x;
    const int tx = tid & 15, ty = tid >> 4;
    const int m0 = blockIdx.y << 6;
    const int n0 = blockIdx.x << 6;
    float c[4][4] = {};

    for (int k0 = 0; k0 < II; k0 += 32) {
#pragma unroll
        for (int hh = 0; hh < 2; ++hh) {
            int row = (tid >> 3) + (hh << 5);
            int col = (tid & 7) << 2;
            float4 va = *(const float4*)(x + (size_t)(m0 + row) * II + k0 + col);
            As[row][col] = va.x; As[row][col + 1] = va.y;
            As[row][col + 2] = va.z; As[row][col + 3] = va.w;
            float4 vb = *(const float4*)(Wx + (size_t)(n0 + row) * II + k0 + col);
            Bs[row][col] = vb.x; Bs[row][col + 1] = vb.y;
            Bs[row][col + 2] = vb.z; Bs[row][col + 3] = vb.w;
        }
        __syncthreads();
#pragma unroll
        for (int kk = 0; kk < 32; ++kk) {
            float a[4], bb[4];
#pragma unroll
            for (int u = 0; u < 4; ++u) a[u] = As[(ty << 2) + u][kk];
#pragma unroll
            for (int v = 0; v < 4; ++v) bb[v] = Bs[(tx << 2) + v][kk];
#pragma unroll
            for (int u = 0; u < 4; ++u)
#pragma unroll
                for (int v = 0; v < 4; ++v)
                    c[u][v] = fmaf(a[u], bb[v], c[u][v]);
        }
        __syncthreads();
    }
    const int n = n0 + (tx << 2);
    float4 bxv = *(const float4*)(bx + n);
    float4 bhv = *(const float4*)(bh + n);
    float4 badd = {bxv.x + bhv.x, bxv.y + bhv.y, bxv.z + bhv.z, bxv.w + bhv.w};
#pragma unroll
    for (int u = 0; u < 4; ++u) {
        int m = m0 + (ty << 2) + u;
        float4 o = {c[u][0] + badd.x, c[u][1] + badd.y,
                    c[u][2] + badd.z, c[u][3] + badd.w};
        *(float4*)(xf + (size_t)m * G4 + n) = o;
    }
}

// ---------------------------------------------------------------------------
// hebb held as 64 NAMED scalar floats per thread (SSA values — cannot be
// demoted to scratch; a float[64] alloca was, per round-1/2 VGPR_Count=64
// and 58 MB of scratch write-back).
// ---------------------------------------------------------------------------
#define HB_FOREACH(X) \
    X(0) X(1) X(2) X(3) X(4) X(5) X(6) X(7) \
    X(8) X(9) X(10) X(11) X(12) X(13) X(14) X(15) \
    X(16) X(17) X(18) X(19) X(20) X(21) X(22) X(23) \
    X(24) X(25) X(26) X(27) X(28) X(29) X(30) X(31) \
    X(32) X(33) X(34) X(35) X(36) X(37) X(38) X(39) \
    X(40) X(41) X(42) X(43) X(44) X(45) X(46) X(47) \
    X(48) X(49) X(50) X(51) X(52) X(53) X(54) X(55) \
    X(56) X(57) X(58) X(59) X(60) X(61) X(62) X(63)

#define HB_DECL(i) float hb##i = 0.0f;
#define HB_OUT(i) hbout[(size_t)(r0 + i) * HH + k] = hb##i;

// update hebb element i with h_old component, then accumulate plast with
// h_new*alpha against the UPDATED value (hebb_t used with h_{t-1}).
#define HB_STEP(i, hoc, hnc, av) \
    hb##i = clip2(fmaf(mj, hoc, hb##i)); \
    pp = fmaf((hnc) * (av), hb##i, pp);

#define HB_CHUNK(q, i0, i1, i2, i3) { \
    float4 ho = hOld4[rbase4 + q]; \
    float4 hn = hNew4[rbase4 + q]; \
    unsigned p0 = abase[(2 * q) << 8]; \
    unsigned p1 = abase[(2 * q + 1) << 8]; \
    HB_STEP(i0, ho.x, hn.x, bflo(p0)) \
    HB_STEP(i1, ho.y, hn.y, bfhi(p0)) \
    HB_STEP(i2, ho.z, hn.z, bflo(p1)) \
    HB_STEP(i3, ho.w, hn.w, bfhi(p1)) }

#define HB_ALL_CHUNKS \
    HB_CHUNK(0, 0, 1, 2, 3)    HB_CHUNK(1, 4, 5, 6, 7) \
    HB_CHUNK(2, 8, 9, 10, 11)  HB_CHUNK(3, 12, 13, 14, 15) \
    HB_CHUNK(4, 16, 17, 18, 19) HB_CHUNK(5, 20, 21, 22, 23) \
    HB_CHUNK(6, 24, 25, 26, 27) HB_CHUNK(7, 28, 29, 30, 31) \
    HB_CHUNK(8, 32, 33, 34, 35) HB_CHUNK(9, 36, 37, 38, 39) \
    HB_CHUNK(10, 40, 41, 42, 43) HB_CHUNK(11, 44, 45, 46, 47) \
    HB_CHUNK(12, 48, 49, 50, 51) HB_CHUNK(13, 52, 53, 54, 55) \
    HB_CHUNK(14, 56, 57, 58, 59) HB_CHUNK(15, 60, 61, 62, 63)

__global__ __launch_bounds__(1024, 1) void scan_kernel(
    const float* __restrict__ xf,      // [T,B,4H], biases folded
    const uint4* __restrict__ Wd,      // f16 interleaved Wh
    const unsigned* __restrict__ alG,  // packed bf16 alpha pairs
    const float* __restrict__ w_mod,
    const float* __restrict__ b_mod,
    const float* __restrict__ w_fan,
    const float* __restrict__ b_fan,
    float* __restrict__ out) {
    const int b   = blockIdx.x;
    const int tid = threadIdx.x;
    const int k   = tid & (HH - 1);
    const int rg  = tid >> 8;        // 0..3
    const int r0  = rg << 6;
    const int rbase4 = r0 >> 2;

    __shared__ alignas(16) float h32_s[2][HH];
    __shared__ alignas(16) unsigned short hf_s[2][HH];
    __shared__ float fioj_s[G4];
    __shared__ float pp_s[4][HH];
    __shared__ float red_s[4];

    HB_FOREACH(HB_DECL)

    if (tid < HH) {
        h32_s[0][tid] = 0.0f; h32_s[1][tid] = 0.0f;
        hf_s[0][tid] = 0;     hf_s[1][tid] = 0;
    }
    if (tid < 4) red_s[tid] = 0.0f;
    __syncthreads();

    const float bmod = b_mod[0];
    const float wf = w_fan[k], bf = b_fan[k], wm = w_mod[k];
    float creg = 0.0f, jreg = 0.0f, hnreg = 0.0f;

    const uint4* wbase = Wd + tid;
    const unsigned* abase = alG + ((r0 >> 1) << 8) + k;
    const float* xfp = xf + (size_t)b * G4 + tid;

    for (int t = 0; t < TT; ++t) {
        float xfv = xfp[(size_t)t * BB * G4];   // prefetch early

        // ---- Phase 1a: eta_{t-1}, deferred hebb update + plast(t), fused --
        float eta = tanhfast(((red_s[0] + red_s[1]) + (red_s[2] + red_s[3])) + bmod);
        float mj = fmaf(eta, wf, bf) * jreg;    // 0 at t=0 (jreg=0)
        const float4* hOld4 = (const float4*)h32_s[t & 1];        // h_{t-2}
        const float4* hNew4 = (const float4*)h32_s[(t & 1) ^ 1];  // h_{t-1}
        float pp = 0.0f;
        HB_ALL_CHUNKS
        pp_s[rg][k] = pp;

        // ---- Phase 1b: gate matvec fioj[tid] via f16 dot2 -----------------
        const uint4* hf4 = (const uint4*)hf_s[(t & 1) ^ 1];
        const uint4* wp = wbase;
        float ac0 = 0.f, ac1 = 0.f, ac2 = 0.f, ac3 = 0.f;
#pragma unroll 8
        for (int r8 = 0; r8 < 32; ++r8) {
            uint4 w = *wp; wp += 1024;
            uint4 hv = hf4[r8];
            ac0 = dot2(w.x, hv.x, ac0);
            ac1 = dot2(w.y, hv.y, ac1);
            ac2 = dot2(w.z, hv.z, ac2);
            ac3 = dot2(w.w, hv.w, ac3);
        }
        fioj_s[tid] = ((ac0 + ac1) + (ac2 + ac3)) + xfv;
        __syncthreads();

        // ---- Phase 2: cell update, redundant across the 4 row-groups ------
        float fg = sigm(fioj_s[k]);
        float ig = sigm(fioj_s[HH + k]);
        float og = sigm(fioj_s[2 * HH + k]);
        float jp = fioj_s[3 * HH + k]
                 + ((pp_s[0][k] + pp_s[1][k]) + (pp_s[2][k] + pp_s[3][k]));
        jreg = tanhfast(jp);
        creg = fmaf(fg, creg, ig * jreg);
        hnreg = og * tanhfast(creg);
        if (rg == 0) {   // waves 0-3, wave-uniform
            h32_s[t & 1][k] = hnreg;
            _Float16 hh = (_Float16)hnreg;
            hf_s[t & 1][k] = __builtin_bit_cast(unsigned short, hh);
            out[((size_t)t * BB + b) * HH + k] = hnreg;
            float e = creg * wm;
#pragma unroll
            for (int m = 32; m >= 1; m >>= 1) e += __shfl_xor(e, m, 64);
            if ((k & 63) == 0) red_s[k >> 6] = e;
        }
        __syncthreads();
    }

    // ---- Final deferred hebb update (step 255's delta) -------------------
    {
        float eta = tanhfast(((red_s[0] + red_s[1]) + (red_s[2] + red_s[3])) + bmod);
        float mj = fmaf(eta, wf, bf) * jreg;
        const float4* hOld4 = (const float4*)h32_s[0];   // h_254 (TT even)
        const float4* hNew4 = (const float4*)h32_s[1];   // unused pp input
        float pp = 0.0f;
        HB_ALL_CHUNKS
        (void)pp;
    }

    const size_t HS = (size_t)TT * BB * HH;
    if (rg == 0) {
        out[HS + (size_t)b * HH + k]           = hnreg;  // h_255
        out[HS + BB * HH + (size_t)b * HH + k] = creg;   // c_255
    }
    float* hbout = out + HS + 2 * BB * HH + (size_t)b * HH * HH;
    HB_FOREACH(HB_OUT)
}

// ---------------------------------------------------------------------------
extern "C" void kernel_launch(void* const* d_in, const int* in_sizes, int n_in,
                              void* d_out, int out_size, void* d_ws,
                              size_t ws_size, hipStream_t stream) {
    const float* x     = (const float*)d_in[0];
    const float* Wx    = (const float*)d_in[1];
    const float* bx    = (const float*)d_in[2];
    const float* Wh    = (const float*)d_in[3];
    const float* bh    = (const float*)d_in[4];
    const float* w_mod = (const float*)d_in[5];
    const float* b_mod = (const float*)d_in[6];
    const float* w_fan = (const float*)d_in[7];
    const float* b_fan = (const float*)d_in[8];
    const float* alpha = (const float*)d_in[9];
    float* out = (float*)d_out;

    float*    xf  = (float*)d_ws;                                  // 32 MiB
    uint4*    Wd  = (uint4*)((char*)d_ws + 33554432);              // 512 KiB
    unsigned* alG = (unsigned*)((char*)d_ws + 33554432 + 524288);  // 128 KiB

    hipLaunchKernelGGL(prep_wd, dim3(128), dim3(256), 0, stream, Wh, Wd);
    hipLaunchKernelGGL(prep_al, dim3(128), dim3(256), 0, stream, alpha, alG);
    hipLaunchKernelGGL(xf_gemm, dim3(16, 128), dim3(256), 0, stream,
                       x, Wx, bx, bh, xf);
    hipLaunchKernelGGL(scan_kernel, dim3(BB), dim3(1024), 0, stream,
                       xf, Wd, alG, w_mod, b_mod, w_fan, b_fan, out);
}

// Round 4
// 2335.170 us; speedup vs baseline: 2.2042x; 1.2328x over previous
//
#include <hip/hip_runtime.h>

// PlasticLSTM: T=256, B=32, I=128, H=256, 4H=1024, CLIP=2
// d_in: x[T,B,I], Wx[4H,I], bx[4H], Wh[4H,H], bh[4H], w_mod[1,H], b_mod[1],
//       w_fan[H,1], b_fan[H], alpha[H,H]   (all fp32)
// d_out: hs[T,B,H] ++ h[B,H] ++ c[B,H] ++ hebb[B,H,H]  (fp32, concat flat)

#define TT 256
#define BB 32
#define II 128
#define HH 256
#define G4 1024

typedef _Float16 h2_t __attribute__((ext_vector_type(2)));

__device__ __forceinline__ float sigm(float x) {
    return 1.0f / (1.0f + __expf(-x));
}
__device__ __forceinline__ float tanhfast(float x) {
    return 1.0f - 2.0f / (__expf(2.0f * x) + 1.0f);
}
__device__ __forceinline__ unsigned pkh(float lo, float hi) {
    h2_t v;
    v.x = (_Float16)lo;
    v.y = (_Float16)hi;
    return __builtin_bit_cast(unsigned, v);
}

#if __has_builtin(__builtin_amdgcn_fdot2)
__device__ __forceinline__ float dot2(unsigned a, unsigned b, float c) {
    return __builtin_amdgcn_fdot2(__builtin_bit_cast(h2_t, a),
                                  __builtin_bit_cast(h2_t, b), c, false);
}
#else
__device__ __forceinline__ float dot2(unsigned a, unsigned b, float c) {
    h2_t av = __builtin_bit_cast(h2_t, a), bv = __builtin_bit_cast(h2_t, b);
    return c + (float)av.x * (float)bv.x + (float)av.y * (float)bv.y;
}
#endif

__device__ __forceinline__ h2_t pkfma(h2_t a, h2_t b, h2_t c) {
#if __has_builtin(__builtin_elementwise_fma)
    return __builtin_elementwise_fma(a, b, c);
#else
    return a * b + c;
#endif
}
__device__ __forceinline__ h2_t clip2h(h2_t x) {
    const h2_t lo = {(_Float16)-2.0f, (_Float16)-2.0f};
    const h2_t hi = {(_Float16)2.0f, (_Float16)2.0f};
#if __has_builtin(__builtin_elementwise_max) && __has_builtin(__builtin_elementwise_min)
    return __builtin_elementwise_min(__builtin_elementwise_max(x, lo), hi);
#else
    h2_t r = x;
    r.x = r.x < lo.x ? lo.x : (r.x > hi.x ? hi.x : r.x);
    r.y = r.y < lo.y ? lo.y : (r.y > hi.y ? hi.y : r.y);
    return r;
#endif
}

// ---------------------------------------------------------------------------
// Wd3 layout: idx = ro*4096 + g*4 + ri  (ro in [0,8), ri in [0,4), g in [0,1024))
//   entry = uint4 of 8 f16 = Wh[g][8*r8 .. 8*r8+7], r8 = 4*ro + ri.
// Per-thread (g=tid) inner reads are 4 consecutive uint4 (imm offsets 0..48),
// one 64B L2 line per lane per outer iter.
// ---------------------------------------------------------------------------
__global__ __launch_bounds__(256) void prep_wd3(const float* __restrict__ Wh,
                                                uint4* __restrict__ Wd3) {
    int idx = blockIdx.x * 256 + threadIdx.x;   // 32768
    int ro = idx >> 12, rem = idx & 4095;
    int g = rem >> 2, ri = rem & 3;
    int r8 = 4 * ro + ri;
    const float4* s = (const float4*)(Wh + (size_t)g * HH + (r8 << 3));
    float4 a = s[0], b2 = s[1];
    uint4 o;
    o.x = pkh(a.x, a.y);
    o.y = pkh(a.z, a.w);
    o.z = pkh(b2.x, b2.y);
    o.w = pkh(b2.z, b2.w);
    Wd3[idx] = o;
}

// ---------------------------------------------------------------------------
// alQ layout: idx = p4*256 + k  ->  uint4; component j = f16 pair
//   { alpha[2*(4*p4+j)][k], alpha[2*(4*p4+j)+1][k] }.
// Thread k reads 8 uint4 per step (its 32 row-pairs), coalesced across k.
// ---------------------------------------------------------------------------
__global__ __launch_bounds__(256) void prep_alq(const float* __restrict__ alpha,
                                                uint4* __restrict__ alQ) {
    int idx = blockIdx.x * 256 + threadIdx.x;   // 8192
    int p4 = idx >> 8, k = idx & 255;
    uint4 o;
    unsigned r[4];
#pragma unroll
    for (int j = 0; j < 4; ++j) {
        int p = 4 * p4 + j;
        float a0 = alpha[(size_t)(2 * p) * HH + k];
        float a1 = alpha[(size_t)(2 * p + 1) * HH + k];
        r[j] = pkh(a0, a1);
    }
    o.x = r[0]; o.y = r[1]; o.z = r[2]; o.w = r[3];
    alQ[idx] = o;
}

// ---------------------------------------------------------------------------
// xf[t,b,g] = sum_i x[t,b,i]*Wx[g,i] + bx[g] + bh[g]
// ---------------------------------------------------------------------------
__global__ __launch_bounds__(256) void xf_gemm(const float* __restrict__ x,
                                               const float* __restrict__ Wx,
                                               const float* __restrict__ bx,
                                               const float* __restrict__ bh,
                                               float* __restrict__ xf) {
    __shared__ float As[64][37];
    __shared__ float Bs[64][37];
    const int tid = threadIdx.x;
    const int tx = tid & 15, ty = tid >> 4;
    const int m0 = blockIdx.y << 6;
    const int n0 = blockIdx.x << 6;
    float c[4][4] = {};

    for (int k0 = 0; k0 < II; k0 += 32) {
#pragma unroll
        for (int hh = 0; hh < 2; ++hh) {
            int row = (tid >> 3) + (hh << 5);
            int col = (tid & 7) << 2;
            float4 va = *(const float4*)(x + (size_t)(m0 + row) * II + k0 + col);
            As[row][col] = va.x; As[row][col + 1] = va.y;
            As[row][col + 2] = va.z; As[row][col + 3] = va.w;
            float4 vb = *(const float4*)(Wx + (size_t)(n0 + row) * II + k0 + col);
            Bs[row][col] = vb.x; Bs[row][col + 1] = vb.y;
            Bs[row][col + 2] = vb.z; Bs[row][col + 3] = vb.w;
        }
        __syncthreads();
#pragma unroll
        for (int kk = 0; kk < 32; ++kk) {
            float a[4], bb[4];
#pragma unroll
            for (int u = 0; u < 4; ++u) a[u] = As[(ty << 2) + u][kk];
#pragma unroll
            for (int v = 0; v < 4; ++v) bb[v] = Bs[(tx << 2) + v][kk];
#pragma unroll
            for (int u = 0; u < 4; ++u)
#pragma unroll
                for (int v = 0; v < 4; ++v)
                    c[u][v] = fmaf(a[u], bb[v], c[u][v]);
        }
        __syncthreads();
    }
    const int n = n0 + (tx << 2);
    float4 bxv = *(const float4*)(bx + n);
    float4 bhv = *(const float4*)(bh + n);
    float4 badd = {bxv.x + bhv.x, bxv.y + bhv.y, bxv.z + bhv.z, bxv.w + bhv.w};
#pragma unroll
    for (int u = 0; u < 4; ++u) {
        int m = m0 + (ty << 2) + u;
        float4 o = {c[u][0] + badd.x, c[u][1] + badd.y,
                    c[u][2] + badd.z, c[u][3] + badd.w};
        *(float4*)(xf + (size_t)m * G4 + n) = o;
    }
}

// ---------------------------------------------------------------------------
// hebb: 32 NAMED half2 registers per thread (rows r0+2i, r0+2i+1, column k).
// Packed math: v_pk_fma_f16 update, pk min/max clip, v_dot2_f32_f16 plast.
// ---------------------------------------------------------------------------
#define HBP_FOREACH(X) \
    X(0) X(1) X(2) X(3) X(4) X(5) X(6) X(7) \
    X(8) X(9) X(10) X(11) X(12) X(13) X(14) X(15) \
    X(16) X(17) X(18) X(19) X(20) X(21) X(22) X(23) \
    X(24) X(25) X(26) X(27) X(28) X(29) X(30) X(31)

#define HBP_DECL(i) h2_t hp##i = {(_Float16)0.0f, (_Float16)0.0f};
#define HBP_OUT(i) \
    hbout[(size_t)(r0 + 2 * i) * HH + k]     = (float)hp##i.x; \
    hbout[(size_t)(r0 + 2 * i + 1) * HH + k] = (float)hp##i.y;

// update pair i (hebb_{t-1} <- clip(hebb_{t-2} + mj*h_old)), then accumulate
// plast_t against the UPDATED pair with h_new*alpha.
#define HBP_STEP(i, au, hou, hnu) { \
    h2_t al2 = __builtin_bit_cast(h2_t, au); \
    h2_t ho2 = __builtin_bit_cast(h2_t, hou); \
    h2_t hn2 = __builtin_bit_cast(h2_t, hnu); \
    hp##i = clip2h(pkfma(mj2, ho2, hp##i)); \
    h2_t hna = hn2 * al2; \
    pp = dot2(__builtin_bit_cast(unsigned, hna), \
              __builtin_bit_cast(unsigned, hp##i), pp); }

#define HBP_CHUNK(q, i0, i1, i2, i3) { \
    uint4 av = aq[(size_t)(q) << 8]; \
    uint4 ho = hfO4[hq0 + (q)]; \
    uint4 hn = hfN4[hq0 + (q)]; \
    HBP_STEP(i0, av.x, ho.x, hn.x) \
    HBP_STEP(i1, av.y, ho.y, hn.y) \
    HBP_STEP(i2, av.z, ho.z, hn.z) \
    HBP_STEP(i3, av.w, ho.w, hn.w) }

#define HBP_ALL_CHUNKS \
    HBP_CHUNK(0, 0, 1, 2, 3)     HBP_CHUNK(1, 4, 5, 6, 7) \
    HBP_CHUNK(2, 8, 9, 10, 11)   HBP_CHUNK(3, 12, 13, 14, 15) \
    HBP_CHUNK(4, 16, 17, 18, 19) HBP_CHUNK(5, 20, 21, 22, 23) \
    HBP_CHUNK(6, 24, 25, 26, 27) HBP_CHUNK(7, 28, 29, 30, 31)

// final deferred update only (no plast)
#define HBU_STEP(i, hou) { \
    h2_t ho2 = __builtin_bit_cast(h2_t, hou); \
    hp##i = clip2h(pkfma(mj2, ho2, hp##i)); }
#define HBU_CHUNK(q, i0, i1, i2, i3) { \
    uint4 ho = hfO4[hq0 + (q)]; \
    HBU_STEP(i0, ho.x) HBU_STEP(i1, ho.y) \
    HBU_STEP(i2, ho.z) HBU_STEP(i3, ho.w) }
#define HBU_ALL_CHUNKS \
    HBU_CHUNK(0, 0, 1, 2, 3)     HBU_CHUNK(1, 4, 5, 6, 7) \
    HBU_CHUNK(2, 8, 9, 10, 11)   HBU_CHUNK(3, 12, 13, 14, 15) \
    HBU_CHUNK(4, 16, 17, 18, 19) HBU_CHUNK(5, 20, 21, 22, 23) \
    HBU_CHUNK(6, 24, 25, 26, 27) HBU_CHUNK(7, 28, 29, 30, 31)

__global__ __launch_bounds__(1024, 1) void scan_kernel(
    const float* __restrict__ xf,      // [T,B,4H], biases folded
    const uint4* __restrict__ Wd3,     // f16 tiled Wh
    const uint4* __restrict__ alQ,     // f16 pair-packed alpha
    const float* __restrict__ w_mod,
    const float* __restrict__ b_mod,
    const float* __restrict__ w_fan,
    const float* __restrict__ b_fan,
    float* __restrict__ out) {
    const int b   = blockIdx.x;
    const int tid = threadIdx.x;
    const int k   = tid & (HH - 1);
    const int rg  = tid >> 8;        // 0..3
    const int r0  = rg << 6;
    const int hq0 = rg << 3;         // uint4 index of row r0 in hf_s

    __shared__ alignas(16) unsigned short hf_s[2][HH];
    __shared__ float fioj_s[G4];
    __shared__ float pp_s[4][HH];
    __shared__ float red_s[4];

    HBP_FOREACH(HBP_DECL)

    if (tid < HH) {
        hf_s[0][tid] = 0;
        hf_s[1][tid] = 0;
    }
    if (tid < 4) red_s[tid] = 0.0f;
    __syncthreads();

    const float bmod = b_mod[0];
    const float wf = w_fan[k], bf = b_fan[k], wm = w_mod[k];
    float creg = 0.0f, jreg = 0.0f, hnreg = 0.0f;

    const uint4* wbase = Wd3 + ((size_t)tid << 2);
    const uint4* aq    = alQ + ((size_t)(rg << 3) << 8) + k;
    const float* xfp   = xf + (size_t)b * G4 + tid;

    for (int t = 0; t < TT; ++t) {
        float xfv = xfp[(size_t)t * BB * G4];   // prefetch early

        // ---- Phase 1a: eta_{t-1}; deferred hebb update + plast(t) fused ---
        float eta = tanhfast(((red_s[0] + red_s[1]) + (red_s[2] + red_s[3])) + bmod);
        float mj = fmaf(eta, wf, bf) * jreg;    // 0 at t=0
        h2_t mj2;
        mj2.x = (_Float16)mj;
        mj2.y = mj2.x;
        const uint4* hfO4 = (const uint4*)hf_s[t & 1];        // h_{t-2}
        const uint4* hfN4 = (const uint4*)hf_s[(t & 1) ^ 1];  // h_{t-1}
        float pp = 0.0f;
        HBP_ALL_CHUNKS
        pp_s[rg][k] = pp;

        // ---- Phase 1b: gate matvec fioj[tid] via f16 dot2 -----------------
        float ac0 = 0.f, ac1 = 0.f, ac2 = 0.f, ac3 = 0.f;
#pragma unroll 2
        for (int ro = 0; ro < 8; ++ro) {
            const uint4* wp = wbase + ((size_t)ro << 12);
            uint4 w0 = wp[0], w1 = wp[1], w2 = wp[2], w3 = wp[3];
            uint4 h0 = hfN4[4 * ro], h1 = hfN4[4 * ro + 1];
            uint4 h2 = hfN4[4 * ro + 2], h3 = hfN4[4 * ro + 3];
            ac0 = dot2(w0.x, h0.x, ac0); ac1 = dot2(w0.y, h0.y, ac1);
            ac2 = dot2(w0.z, h0.z, ac2); ac3 = dot2(w0.w, h0.w, ac3);
            ac0 = dot2(w1.x, h1.x, ac0); ac1 = dot2(w1.y, h1.y, ac1);
            ac2 = dot2(w1.z, h1.z, ac2); ac3 = dot2(w1.w, h1.w, ac3);
            ac0 = dot2(w2.x, h2.x, ac0); ac1 = dot2(w2.y, h2.y, ac1);
            ac2 = dot2(w2.z, h2.z, ac2); ac3 = dot2(w2.w, h2.w, ac3);
            ac0 = dot2(w3.x, h3.x, ac0); ac1 = dot2(w3.y, h3.y, ac1);
            ac2 = dot2(w3.z, h3.z, ac2); ac3 = dot2(w3.w, h3.w, ac3);
        }
        fioj_s[tid] = ((ac0 + ac1) + (ac2 + ac3)) + xfv;
        __syncthreads();

        // ---- Phase 2: cell update, redundant across the 4 row-groups ------
        float fg = sigm(fioj_s[k]);
        float ig = sigm(fioj_s[HH + k]);
        float og = sigm(fioj_s[2 * HH + k]);
        float jp = fioj_s[3 * HH + k]
                 + ((pp_s[0][k] + pp_s[1][k]) + (pp_s[2][k] + pp_s[3][k]));
        jreg = tanhfast(jp);
        creg = fmaf(fg, creg, ig * jreg);
        hnreg = og * tanhfast(creg);
        if (rg == 0) {   // waves 0-3, wave-uniform
            _Float16 hh = (_Float16)hnreg;
            hf_s[t & 1][k] = __builtin_bit_cast(unsigned short, hh);
            out[((size_t)t * BB + b) * HH + k] = hnreg;
            float e = creg * wm;
#pragma unroll
            for (int m = 32; m >= 1; m >>= 1) e += __shfl_xor(e, m, 64);
            if ((k & 63) == 0) red_s[k >> 6] = e;
        }
        __syncthreads();
    }

    // ---- Final deferred hebb update (step 255's delta) -------------------
    {
        float eta = tanhfast(((red_s[0] + red_s[1]) + (red_s[2] + red_s[3])) + bmod);
        float mj = fmaf(eta, wf, bf) * jreg;
        h2_t mj2;
        mj2.x = (_Float16)mj;
        mj2.y = mj2.x;
        const uint4* hfO4 = (const uint4*)hf_s[0];   // h_254 (TT even)
        HBU_ALL_CHUNKS
    }

    const size_t HS = (size_t)TT * BB * HH;
    if (rg == 0) {
        out[HS + (size_t)b * HH + k]           = hnreg;  // h_255
        out[HS + BB * HH + (size_t)b * HH + k] = creg;   // c_255
    }
    float* hbout = out + HS + 2 * BB * HH + (size_t)b * HH * HH;
    HBP_FOREACH(HBP_OUT)
}

// ---------------------------------------------------------------------------
extern "C" void kernel_launch(void* const* d_in, const int* in_sizes, int n_in,
                              void* d_out, int out_size, void* d_ws,
                              size_t ws_size, hipStream_t stream) {
    const float* x     = (const float*)d_in[0];
    const float* Wx    = (const float*)d_in[1];
    const float* bx    = (const float*)d_in[2];
    const float* Wh    = (const float*)d_in[3];
    const float* bh    = (const float*)d_in[4];
    const float* w_mod = (const float*)d_in[5];
    const float* b_mod = (const float*)d_in[6];
    const float* w_fan = (const float*)d_in[7];
    const float* b_fan = (const float*)d_in[8];
    const float* alpha = (const float*)d_in[9];
    float* out = (float*)d_out;

    float* xf  = (float*)d_ws;                                   // 32 MiB
    uint4* Wd3 = (uint4*)((char*)d_ws + 33554432);                // 512 KiB
    uint4* alQ = (uint4*)((char*)d_ws + 33554432 + 524288);       // 128 KiB

    hipLaunchKernelGGL(prep_wd3, dim3(128), dim3(256), 0, stream, Wh, Wd3);
    hipLaunchKernelGGL(prep_alq, dim3(32), dim3(256), 0, stream, alpha, alQ);
    hipLaunchKernelGGL(xf_gemm, dim3(16, 128), dim3(256), 0, stream,
                       x, Wx, bx, bh, xf);
    hipLaunchKernelGGL(scan_kernel, dim3(BB), dim3(1024), 0, stream,
                       xf, Wd3, alQ, w_mod, b_mod, w_fan, b_fan, out);
}